// Round 16
// baseline (289.397 us; speedup 1.0000x reference)
//
#include <hip/hip_runtime.h>

typedef __attribute__((ext_vector_type(8))) short short8;
typedef __attribute__((ext_vector_type(4))) float f32x4;

#define BB 16
#define MM 2048
#define NN 2048

static __device__ __forceinline__ unsigned int cvtpk(float lo, float hi) {
  unsigned int r;
  asm("v_cvt_pk_bf16_f32 %0, %1, %2" : "=v"(r) : "v"(lo), "v"(hi));
  return r;
}
static __device__ __forceinline__ float rdlane(float v, int l) {
  return __uint_as_float(__builtin_amdgcn_readlane(__float_as_uint(v), l));
}

// in: [B, nrows, 64] f32 -> out: [B, 64, nrows] bf16
__global__ void transpose_cvt(const float* __restrict__ in,
                              unsigned short* __restrict__ out, int nrows) {
  __shared__ float t[64][65];
  int b = blockIdx.y;
  int n0 = blockIdx.x * 64;
  int tid = threadIdx.x;
  int lane = tid & 63;
  int q = tid >> 6;
  const float* inb = in + ((size_t)b * nrows + n0) * 64;
#pragma unroll
  for (int i = 0; i < 16; ++i) {
    int n = q * 16 + i;
    t[n][lane] = inb[n * 64 + lane];
  }
  __syncthreads();
  unsigned short* outb = out + (size_t)b * 64 * nrows + n0;
  int pr = tid & 31, rq = tid >> 5;
#pragma unroll
  for (int i = 0; i < 8; ++i) {
    int r = rq + 8 * i;
    int n = 2 * pr;
    *(unsigned int*)(outb + (size_t)r * nrows + n) = cvtpk(t[n][r], t[n + 1][r]);
  }
}

// Gram: bmat[b] = T * T^T, T = [64, K] bf16 row-major. grid (B), block 256.
__global__ void gemm_gram2(const unsigned short* __restrict__ tT,
                           float* __restrict__ bmat, int K) {
  __shared__ float part[4][64][65];
  int b = blockIdx.x;
  int tid = threadIdx.x;
  int w = tid >> 6, l = tid & 63;
  int lr = l & 15, g = l >> 4;
  const unsigned short* vb = tT + (size_t)b * 64 * K;
  int kslice = K >> 2;
  int kbase = w * kslice;
  f32x4 acc[4][4] = {};
  for (int kk = 0; kk < kslice; kk += 32) {
    int k = kbase + kk + 8 * g;
    short8 fr[4];
#pragma unroll
    for (int rt = 0; rt < 4; ++rt)
      fr[rt] = *(const short8*)(vb + (size_t)(rt * 16 + lr) * K + k);
#pragma unroll
    for (int rt = 0; rt < 4; ++rt)
#pragma unroll
      for (int ct = 0; ct < 4; ++ct)
        acc[rt][ct] = __builtin_amdgcn_mfma_f32_16x16x32_bf16(fr[rt], fr[ct], acc[rt][ct], 0, 0, 0);
  }
#pragma unroll
  for (int rt = 0; rt < 4; ++rt)
#pragma unroll
    for (int ct = 0; ct < 4; ++ct)
#pragma unroll
      for (int j = 0; j < 4; ++j)
        part[w][rt * 16 + 4 * g + j][ct * 16 + lr] = acc[rt][ct][j];
  __syncthreads();
  float* bb = bmat + b * 4096;
  for (int i = tid; i < 4096; i += 256) {
    int row = i >> 6, col = i & 63;
    bb[i] = part[0][row][col] + part[1][row][col] + part[2][row][col] + part[3][row][col];
  }
}

// a[b][m][r] = sum_n x[b][m][n] * v[b][n][r];  vT = [B,64,N] bf16
// DIRECT-LOAD + B-REG DOUBLE BUFFER: B-fragments prefetched one chunk ahead
// into the alternate register buffer, so the MFMA's waitcnt is for loads
// ~8 deep in the vmcnt FIFO (compiler emits vmcnt(~6), never 0) -> the
// 4-deep x pipeline never drains. No LDS, no barriers.
// grid (M/64, B), block 256.
__global__ void __launch_bounds__(256, 2)
gemm_xv(const float* __restrict__ x,
        const unsigned short* __restrict__ vT,
        float* __restrict__ a) {
  int b = blockIdx.y;
  int m0 = blockIdx.x * 64;
  int tid = threadIdx.x;
  int w = tid >> 6, l = tid & 63;
  int lr = l & 15, g = l >> 4;
  const unsigned short* vb = vT + (size_t)b * 64 * NN;
  const float* xrow = x + (size_t)b * MM * NN + (size_t)(m0 + w * 16 + lr) * NN + 8 * g;
  f32x4 acc[4] = {};
  f32x4 p0[2], p1[2], p2[2], p3[2];
  short8 bA[4], bB[4];

#define XVLD(P, C)                                              \
  {                                                             \
    const f32x4* xp = (const f32x4*)(xrow + (C) * 32);          \
    P[0] = xp[0];                                               \
    P[1] = xp[1];                                               \
  }
#define BLD(BUF, C)                                                             \
  {                                                                             \
    _Pragma("unroll")                                                           \
    for (int ct = 0; ct < 4; ++ct)                                              \
      BUF[ct] = *(const short8*)(vb + (size_t)(ct * 16 + lr) * NN +             \
                                 (C) * 32 + 8 * g);                             \
  }
#define XVUSE(P, BUF)                                                           \
  {                                                                             \
    union { short8 s; unsigned int u[4]; } af;                                  \
    af.u[0] = cvtpk(P[0][0], P[0][1]);                                          \
    af.u[1] = cvtpk(P[0][2], P[0][3]);                                          \
    af.u[2] = cvtpk(P[1][0], P[1][1]);                                          \
    af.u[3] = cvtpk(P[1][2], P[1][3]);                                          \
    _Pragma("unroll")                                                           \
    for (int ct = 0; ct < 4; ++ct)                                              \
      acc[ct] = __builtin_amdgcn_mfma_f32_16x16x32_bf16(af.s, BUF[ct], acc[ct], \
                                                        0, 0, 0);               \
  }

  XVLD(p0, 0); XVLD(p1, 1); XVLD(p2, 2); XVLD(p3, 3);
  BLD(bA, 0);
  for (int c = 0; c < 60; c += 4) {
    BLD(bB, c + 1); XVUSE(p0, bA); XVLD(p0, c + 4);
    BLD(bA, c + 2); XVUSE(p1, bB); XVLD(p1, c + 5);
    BLD(bB, c + 3); XVUSE(p2, bA); XVLD(p2, c + 6);
    BLD(bA, c + 4); XVUSE(p3, bB); XVLD(p3, c + 7);
  }
  BLD(bB, 61); XVUSE(p0, bA);
  BLD(bA, 62); XVUSE(p1, bB);
  BLD(bB, 63); XVUSE(p2, bA);
  XVUSE(p3, bB);
#undef XVLD
#undef BLD
#undef XVUSE

  float* ab = a + ((size_t)b * MM + m0 + w * 16) * 64;
#pragma unroll
  for (int ct = 0; ct < 4; ++ct)
#pragma unroll
    for (int j = 0; j < 4; ++j)
      ab[(size_t)(4 * g + j) * 64 + ct * 16 + lr] = acc[ct][j];
}

// a[b][n][r] = sum_m x[b][m][n] * u[b][m][r];  uT = [B,64,M] bf16
// Same B-reg double-buffer treatment; x gathered per-column (8 dwords/step).
// Batch order reversed for L3 hits. grid (N/64, B), block 256.
__global__ void __launch_bounds__(256, 2)
gemm_xtu(const float* __restrict__ x,
         const unsigned short* __restrict__ uT,
         float* __restrict__ a) {
  int b = (BB - 1) - blockIdx.y;
  int n0 = blockIdx.x * 64;
  int tid = threadIdx.x;
  int w = tid >> 6, l = tid & 63;
  int lr = l & 15, g = l >> 4;
  const unsigned short* ub = uT + (size_t)b * 64 * MM;
  const float* xcol = x + (size_t)b * MM * NN + (size_t)(8 * g) * NN + n0 + w * 16 + lr;
  f32x4 acc[4] = {};
  float s0[8], s1[8], s2[8], s3[8];
  short8 bA[4], bB[4];

#define XTLD(P, C)                                              \
  {                                                             \
    _Pragma("unroll")                                           \
    for (int j = 0; j < 8; ++j)                                 \
      P[j] = xcol[(size_t)((C) * 32 + j) * NN];                 \
  }
#define BLD(BUF, C)                                                             \
  {                                                                             \
    _Pragma("unroll")                                                           \
    for (int ct = 0; ct < 4; ++ct)                                              \
      BUF[ct] = *(const short8*)(ub + (size_t)(ct * 16 + lr) * MM +             \
                                 (C) * 32 + 8 * g);                             \
  }
#define XTUSE(P, BUF)                                                           \
  {                                                                             \
    union { short8 s; unsigned int u[4]; } af;                                  \
    af.u[0] = cvtpk(P[0], P[1]);                                                \
    af.u[1] = cvtpk(P[2], P[3]);                                                \
    af.u[2] = cvtpk(P[4], P[5]);                                                \
    af.u[3] = cvtpk(P[6], P[7]);                                                \
    _Pragma("unroll")                                                           \
    for (int ct = 0; ct < 4; ++ct)                                              \
      acc[ct] = __builtin_amdgcn_mfma_f32_16x16x32_bf16(af.s, BUF[ct], acc[ct], \
                                                        0, 0, 0);               \
  }

  XTLD(s0, 0); XTLD(s1, 1); XTLD(s2, 2); XTLD(s3, 3);
  BLD(bA, 0);
  for (int c = 0; c < 60; c += 4) {
    BLD(bB, c + 1); XTUSE(s0, bA); XTLD(s0, c + 4);
    BLD(bA, c + 2); XTUSE(s1, bB); XTLD(s1, c + 5);
    BLD(bB, c + 3); XTUSE(s2, bA); XTLD(s2, c + 6);
    BLD(bA, c + 4); XTUSE(s3, bB); XTLD(s3, c + 7);
  }
  BLD(bB, 61); XTUSE(s0, bA);
  BLD(bA, 62); XTUSE(s1, bB);
  BLD(bB, 63); XTUSE(s2, bA);
  XTUSE(s3, bB);
#undef XTLD
#undef BLD
#undef XTUSE

  float* ab = a + ((size_t)b * NN + n0 + w * 16) * 64;
#pragma unroll
  for (int ct = 0; ct < 4; ++ct)
#pragma unroll
    for (int j = 0; j < 4; ++j)
      ab[(size_t)(4 * g + j) * 64 + ct * 16 + lr] = acc[ct][j];
}

// Coordinate descent, one THREAD per row: u[64], a[64] live in VGPRs,
// b reads are thread-invariant -> s_load + SGPR fmac operands.
// grid (nrows/64, B), block 64 (1 wave).
__global__ void __launch_bounds__(64, 1)
cd_kernel2(const float* __restrict__ u_in,
           const float* __restrict__ a_ws,
           const float* __restrict__ bmat,
           float* __restrict__ u_out,
           float l1, float l2e, int nrows) {
  int b = blockIdx.y;
  int m = blockIdx.x * 64 + threadIdx.x;
  size_t base = ((size_t)b * nrows + m) * 64;
  const float* bb = bmat + b * 4096;
  float uu[64], aa[64];
#pragma unroll
  for (int i = 0; i < 16; ++i) {
    *(f32x4*)(uu + 4 * i) = *(const f32x4*)(u_in + base + 4 * i);
    *(f32x4*)(aa + 4 * i) = *(const f32x4*)(a_ws + base + 4 * i);
  }
  int lane = threadIdx.x;
  float invl = 1.0f / (bb[lane * 65] + l2e);
#pragma unroll
  for (int r = 0; r < 64; ++r) {
    float s0 = 0.f, s1 = 0.f, s2 = 0.f, s3 = 0.f;
#pragma unroll
    for (int j = 0; j < 64; j += 4) {
      s0 = fmaf(uu[j + 0], bb[r * 64 + j + 0], s0);
      s1 = fmaf(uu[j + 1], bb[r * 64 + j + 1], s1);
      s2 = fmaf(uu[j + 2], bb[r * 64 + j + 2], s2);
      s3 = fmaf(uu[j + 3], bb[r * 64 + j + 3], s3);
    }
    float s = (s0 + s1) + (s2 + s3);
    float brr = bb[r * 65];                      // uniform -> SGPR
    float num = fmaf(uu[r], brr, aa[r] - s);     // a_r - (s - u_r*b_rr)
    float cl = fminf(fmaxf(num, -l1), l1);       // v_med3
    uu[r] = (num - cl) * rdlane(invl, r);        // soft-thr / (b_rr+l2e)
  }
#pragma unroll
  for (int i = 0; i < 16; ++i)
    *(f32x4*)(u_out + base + 4 * i) = *(const f32x4*)(uu + 4 * i);
}

extern "C" void kernel_launch(void* const* d_in, const int* in_sizes, int n_in,
                              void* d_out, int out_size, void* d_ws, size_t ws_size,
                              hipStream_t stream) {
  (void)in_sizes; (void)n_in; (void)out_size; (void)ws_size;
  const float* x = (const float*)d_in[0];
  const float* u = (const float*)d_in[1];
  const float* v = (const float*)d_in[2];
  float* u_out = (float*)d_out;
  float* v_out = u_out + (size_t)BB * MM * 64;

  float* a_ws = (float*)d_ws;                                        // 8.39 MB
  float* b_ws = (float*)((char*)d_ws + (size_t)BB * MM * 64 * 4);    // 256 KB
  unsigned short* tT = (unsigned short*)((char*)b_ws + (size_t)BB * 4096 * 4);

  float l1u = (float)(0.01 * 0.1 * (double)NN);
  float l2u = (float)(0.01 * 0.9 * (double)NN + 1e-16);
  float l1v = (float)(0.01 * 0.1 * (double)MM);
  float l2v = (float)(0.01 * 0.9 * (double)MM + 1e-16);

  // ---- factor 0: update u ----
  transpose_cvt<<<dim3(NN / 64, BB), 256, 0, stream>>>(v, tT, NN);
  gemm_gram2<<<dim3(BB), 256, 0, stream>>>(tT, b_ws, NN);
  gemm_xv<<<dim3(MM / 64, BB), 256, 0, stream>>>(x, tT, a_ws);
  cd_kernel2<<<dim3(MM / 64, BB), 64, 0, stream>>>(u, a_ws, b_ws, u_out, l1u, l2u, MM);

  // ---- factor 1: update v (uses new u) ----
  transpose_cvt<<<dim3(MM / 64, BB), 256, 0, stream>>>(u_out, tT, MM);
  gemm_gram2<<<dim3(BB), 256, 0, stream>>>(tT, b_ws, MM);
  gemm_xtu<<<dim3(NN / 64, BB), 256, 0, stream>>>(x, tT, a_ws);
  cd_kernel2<<<dim3(NN / 64, BB), 64, 0, stream>>>(v, a_ws, b_ws, v_out, l1v, l2v, NN);
}

// Round 17
// 238.270 us; speedup vs baseline: 1.2146x; 1.2146x over previous
//
#include <hip/hip_runtime.h>

typedef __attribute__((ext_vector_type(8))) short short8;
typedef __attribute__((ext_vector_type(4))) float f32x4;

#define BB 16
#define MM 2048
#define NN 2048

static __device__ __forceinline__ unsigned int cvtpk(float lo, float hi) {
  unsigned int r;
  asm("v_cvt_pk_bf16_f32 %0, %1, %2" : "=v"(r) : "v"(lo), "v"(hi));
  return r;
}
static __device__ __forceinline__ float rdlane(float v, int l) {
  return __uint_as_float(__builtin_amdgcn_readlane(__float_as_uint(v), l));
}

// in: [B, nrows, 64] f32 -> out: [B, 64, nrows] bf16  (used once, for v)
__global__ void transpose_cvt(const float* __restrict__ in,
                              unsigned short* __restrict__ out, int nrows) {
  __shared__ float t[64][65];
  int b = blockIdx.y;
  int n0 = blockIdx.x * 64;
  int tid = threadIdx.x;
  int lane = tid & 63;
  int q = tid >> 6;
  const float* inb = in + ((size_t)b * nrows + n0) * 64;
#pragma unroll
  for (int i = 0; i < 16; ++i) {
    int n = q * 16 + i;
    t[n][lane] = inb[n * 64 + lane];
  }
  __syncthreads();
  unsigned short* outb = out + (size_t)b * 64 * nrows + n0;
  int pr = tid & 31, rq = tid >> 5;
#pragma unroll
  for (int i = 0; i < 8; ++i) {
    int r = rq + 8 * i;
    int n = 2 * pr;
    *(unsigned int*)(outb + (size_t)r * nrows + n) = cvtpk(t[n][r], t[n + 1][r]);
  }
}

// a[b][m][r] = sum_n x[b][m][n] * v[b][n][r]  AND  bmat[b] = vT*vT^T (gram,
// fused: B-fragments already stream the full vT per wave, so 4 extra MFMAs
// per kh compute the gram with zero extra loads; every block writes the
// bitwise-identical bmat -> racy-but-identical, deterministic).
// Register-rotated ct=(w+i)&3 keeps all register indices static.
// Body otherwise = r9 structure (best measured). grid (M/64, B), block 256.
__global__ void __launch_bounds__(256, 2)
gemm_xv_g(const float* __restrict__ x,
          const unsigned short* __restrict__ vT,
          float* __restrict__ a, float* __restrict__ bmat) {
  __shared__ char smem[32768];
  int b = blockIdx.y;
  int m0 = blockIdx.x * 64;
  int tid = threadIdx.x;
  int w = tid >> 6, l = tid & 63;
  int lr = l & 15, g = l >> 4;
  const unsigned short* vb = vT + (size_t)b * 64 * NN;
  const char* xg0 = (const char*)x + ((size_t)b * MM + m0) * (size_t)(NN * 4);
  f32x4 acc[4] = {};
  f32x4 gacc[4] = {};
  int rowb = (w * 16 + lr) * 256;
  int key = lr & 7;

#define XVSTAGE(DB, CH)                                                         \
  {                                                                             \
    char* lbs = (char*)smem + (DB)*16384;                                       \
    _Pragma("unroll")                                                           \
    for (int i = 0; i < 4; ++i) {                                               \
      int s = w * 4 + i;                                                        \
      int lg = ((l & 15) ^ ((s & 1) * 4 + (l >> 4))) * 16;                      \
      const char* gp = xg0 + (size_t)(s * 4 + (l >> 4)) * (NN * 4) +            \
                       (CH)*256 + lg;                                           \
      __builtin_amdgcn_global_load_lds(                                         \
          (const __attribute__((address_space(1))) unsigned int*)gp,            \
          (__attribute__((address_space(3))) unsigned int*)(lbs + s * 1024),    \
          16, 0, 0);                                                            \
    }                                                                           \
  }

  XVSTAGE(0, 0);
  __syncthreads();
  for (int c = 0; c < 32; ++c) {
    int db = c & 1;
    if (c + 1 < 32) XVSTAGE(db ^ 1, c + 1);
    const char* lb = (const char*)smem + db * 16384 + rowb;
#pragma unroll
    for (int kh = 0; kh < 2; ++kh) {
      f32x4 lo = *(const f32x4*)(lb + ((kh * 8 + 2 * g + 0) ^ key) * 16);
      f32x4 hi = *(const f32x4*)(lb + ((kh * 8 + 2 * g + 1) ^ key) * 16);
      union { short8 s; unsigned int u[4]; } af;
      af.u[0] = cvtpk(lo[0], lo[1]);
      af.u[1] = cvtpk(lo[2], lo[3]);
      af.u[2] = cvtpk(hi[0], hi[1]);
      af.u[3] = cvtpk(hi[2], hi[3]);
      int k = c * 64 + kh * 32 + 8 * g;
      short8 bfbuf[4];
#pragma unroll
      for (int i = 0; i < 4; ++i) {
        int ctv = (w + i) & 3;
        bfbuf[i] = *(const short8*)(vb + (size_t)(ctv * 16 + lr) * NN + k);
      }
#pragma unroll
      for (int i = 0; i < 4; ++i)
        acc[i] = __builtin_amdgcn_mfma_f32_16x16x32_bf16(af.s, bfbuf[i], acc[i], 0, 0, 0);
#pragma unroll
      for (int i = 0; i < 4; ++i)
        gacc[i] = __builtin_amdgcn_mfma_f32_16x16x32_bf16(bfbuf[0], bfbuf[i], gacc[i], 0, 0, 0);
    }
    __syncthreads();
  }
#undef XVSTAGE

  float* ab = a + ((size_t)b * MM + m0 + w * 16) * 64;
#pragma unroll
  for (int i = 0; i < 4; ++i) {
    int ctv = (w + i) & 3;
#pragma unroll
    for (int j = 0; j < 4; ++j)
      ab[(size_t)(4 * g + j) * 64 + ctv * 16 + lr] = acc[i][j];
  }
  // gram: C[4g+j][lr] of (rowblock w, colblock ctv); identical across blocks
  float* bbw = bmat + b * 4096;
#pragma unroll
  for (int i = 0; i < 4; ++i) {
    int ctv = (w + i) & 3;
#pragma unroll
    for (int j = 0; j < 4; ++j)
      bbw[(w * 16 + 4 * g + j) * 64 + ctv * 16 + lr] = gacc[i][j];
  }
}

// a[b][n][r] = sum_m x[b][m][n] * u[b][m][r]  AND  bmat[b] = uT*uT^T (fused
// gram, same mechanism). Body = r9 xtu. Batch order reversed for L3 hits.
// grid (N/64, B), block 256.
__global__ void __launch_bounds__(256, 2)
gemm_xtu_g(const float* __restrict__ x,
           const unsigned short* __restrict__ uT,
           float* __restrict__ a, float* __restrict__ bmat) {
  __shared__ char smem[32768];
  int b = (BB - 1) - blockIdx.y;
  int n0 = blockIdx.x * 64;
  int tid = threadIdx.x;
  int w = tid >> 6, l = tid & 63;
  int lr = l & 15, g = l >> 4;
  const unsigned short* ub = uT + (size_t)b * 64 * MM;
  const char* xg0 = (const char*)x + ((size_t)b * MM * NN + n0) * 4;
  f32x4 acc[4] = {};
  f32x4 gacc[4] = {};
  int slotX = ((w * 4 + (lr >> 2)) ^ ((g & 1) << 2)) * 16 + (lr & 3) * 4;

#define XTSTAGE(DB, CH)                                                         \
  {                                                                             \
    char* lbs = (char*)smem + (DB)*16384;                                       \
    _Pragma("unroll")                                                           \
    for (int i = 0; i < 4; ++i) {                                               \
      int s = w * 4 + i;                                                        \
      int lg = ((l & 15) ^ (((s >> 1) & 1) << 2)) * 16;                         \
      const char* gp = xg0 + (size_t)((CH)*64 + s * 4 + (l >> 4)) * (NN * 4) +  \
                       lg;                                                      \
      __builtin_amdgcn_global_load_lds(                                         \
          (const __attribute__((address_space(1))) unsigned int*)gp,            \
          (__attribute__((address_space(3))) unsigned int*)(lbs + s * 1024),    \
          16, 0, 0);                                                            \
    }                                                                           \
  }

  XTSTAGE(0, 0);
  __syncthreads();
  for (int c = 0; c < 32; ++c) {
    int db = c & 1;
    if (c + 1 < 32) XTSTAGE(db ^ 1, c + 1);
    const char* lb = (const char*)smem + db * 16384 + slotX;
#pragma unroll
    for (int kh = 0; kh < 2; ++kh) {
      const char* lk = lb + (kh * 32 + 8 * g) * 256;
      float vv[8];
#pragma unroll
      for (int j = 0; j < 8; ++j)
        vv[j] = *(const float*)(lk + j * 256);
      union { short8 s; unsigned int u[4]; } af;
      af.u[0] = cvtpk(vv[0], vv[1]);
      af.u[1] = cvtpk(vv[2], vv[3]);
      af.u[2] = cvtpk(vv[4], vv[5]);
      af.u[3] = cvtpk(vv[6], vv[7]);
      int k = c * 64 + kh * 32 + 8 * g;
      short8 bfbuf[4];
#pragma unroll
      for (int i = 0; i < 4; ++i) {
        int ctv = (w + i) & 3;
        bfbuf[i] = *(const short8*)(ub + (size_t)(ctv * 16 + lr) * MM + k);
      }
#pragma unroll
      for (int i = 0; i < 4; ++i)
        acc[i] = __builtin_amdgcn_mfma_f32_16x16x32_bf16(af.s, bfbuf[i], acc[i], 0, 0, 0);
#pragma unroll
      for (int i = 0; i < 4; ++i)
        gacc[i] = __builtin_amdgcn_mfma_f32_16x16x32_bf16(bfbuf[0], bfbuf[i], gacc[i], 0, 0, 0);
    }
    __syncthreads();
  }
#undef XTSTAGE

  float* ab = a + ((size_t)b * NN + n0 + w * 16) * 64;
#pragma unroll
  for (int i = 0; i < 4; ++i) {
    int ctv = (w + i) & 3;
#pragma unroll
    for (int j = 0; j < 4; ++j)
      ab[(size_t)(4 * g + j) * 64 + ctv * 16 + lr] = acc[i][j];
  }
  float* bbw = bmat + b * 4096;
#pragma unroll
  for (int i = 0; i < 4; ++i) {
    int ctv = (w + i) & 3;
#pragma unroll
    for (int j = 0; j < 4; ++j)
      bbw[(w * 16 + 4 * g + j) * 64 + ctv * 16 + lr] = gacc[i][j];
  }
}

// Coordinate descent, one THREAD per row, PLUS fused bf16-transpose output
// (block = 64 rows x 64 cols = one transpose tile; kills the standalone
// transpose_cvt dispatch + 12MB round-trip). doT: write uT for next factor.
// grid (nrows/64, B), block 64 (1 wave).
__global__ void __launch_bounds__(64, 1)
cd_t(const float* __restrict__ u_in,
     const float* __restrict__ a_ws,
     const float* __restrict__ bmat,
     float* __restrict__ u_out,
     unsigned short* __restrict__ tT,
     float l1, float l2e, int nrows, int doT) {
  __shared__ float ls[64][65];
  int b = blockIdx.y;
  int m0 = blockIdx.x * 64;
  int t = threadIdx.x;
  size_t base = ((size_t)b * nrows + m0 + t) * 64;
  const float* bb = bmat + b * 4096;
  float uu[64], aa[64];
#pragma unroll
  for (int i = 0; i < 16; ++i) {
    *(f32x4*)(uu + 4 * i) = *(const f32x4*)(u_in + base + 4 * i);
    *(f32x4*)(aa + 4 * i) = *(const f32x4*)(a_ws + base + 4 * i);
  }
  float invl = 1.0f / (bb[t * 65] + l2e);
#pragma unroll
  for (int r = 0; r < 64; ++r) {
    float s0 = 0.f, s1 = 0.f, s2 = 0.f, s3 = 0.f;
#pragma unroll
    for (int j = 0; j < 64; j += 4) {
      s0 = fmaf(uu[j + 0], bb[r * 64 + j + 0], s0);
      s1 = fmaf(uu[j + 1], bb[r * 64 + j + 1], s1);
      s2 = fmaf(uu[j + 2], bb[r * 64 + j + 2], s2);
      s3 = fmaf(uu[j + 3], bb[r * 64 + j + 3], s3);
    }
    float s = (s0 + s1) + (s2 + s3);
    float brr = bb[r * 65];                      // uniform -> SGPR
    float num = fmaf(uu[r], brr, aa[r] - s);     // a_r - (s - u_r*b_rr)
    float cl = fminf(fmaxf(num, -l1), l1);       // v_med3
    uu[r] = (num - cl) * rdlane(invl, r);        // soft-thr / (b_rr+l2e)
  }
#pragma unroll
  for (int i = 0; i < 16; ++i)
    *(f32x4*)(u_out + base + 4 * i) = *(const f32x4*)(uu + 4 * i);

  if (doT) {
#pragma unroll
    for (int j = 0; j < 64; ++j) ls[t][j] = uu[j];  // (t+j)%32 -> conflict-free
    __syncthreads();
    unsigned short* outb = tT + (size_t)b * 64 * nrows + m0;
    int q = t & 31, h = t >> 5;
#pragma unroll
    for (int cc = 0; cc < 32; ++cc) {
      int c0 = cc * 2 + h;
      *(unsigned int*)(outb + (size_t)c0 * nrows + 2 * q) =
          cvtpk(ls[2 * q][c0], ls[2 * q + 1][c0]);
    }
  }
}

extern "C" void kernel_launch(void* const* d_in, const int* in_sizes, int n_in,
                              void* d_out, int out_size, void* d_ws, size_t ws_size,
                              hipStream_t stream) {
  (void)in_sizes; (void)n_in; (void)out_size; (void)ws_size;
  const float* x = (const float*)d_in[0];
  const float* u = (const float*)d_in[1];
  const float* v = (const float*)d_in[2];
  float* u_out = (float*)d_out;
  float* v_out = u_out + (size_t)BB * MM * 64;

  float* a_ws = (float*)d_ws;                                        // 8.39 MB
  float* b_ws = (float*)((char*)d_ws + (size_t)BB * MM * 64 * 4);    // 256 KB
  unsigned short* tT = (unsigned short*)((char*)b_ws + (size_t)BB * 4096 * 4);

  float l1u = (float)(0.01 * 0.1 * (double)NN);
  float l2u = (float)(0.01 * 0.9 * (double)NN + 1e-16);
  float l1v = (float)(0.01 * 0.1 * (double)MM);
  float l2v = (float)(0.01 * 0.9 * (double)MM + 1e-16);

  // ---- factor 0: update u (gram fused into xv; uT emitted by cd) ----
  transpose_cvt<<<dim3(NN / 64, BB), 256, 0, stream>>>(v, tT, NN);
  gemm_xv_g<<<dim3(MM / 64, BB), 256, 0, stream>>>(x, tT, a_ws, b_ws);
  cd_t<<<dim3(MM / 64, BB), 64, 0, stream>>>(u, a_ws, b_ws, u_out, tT, l1u, l2u, MM, 1);

  // ---- factor 1: update v (uses new u via tT; gram fused into xtu) ----
  gemm_xtu_g<<<dim3(NN / 64, BB), 256, 0, stream>>>(x, tT, a_ws, b_ws);
  cd_t<<<dim3(NN / 64, BB), 64, 0, stream>>>(v, a_ws, b_ws, v_out, tT, l1v, l2v, NN, 0);
}

// Round 18
// 187.260 us; speedup vs baseline: 1.5454x; 1.2724x over previous
//
#include <hip/hip_runtime.h>

typedef __attribute__((ext_vector_type(8))) short short8;
typedef __attribute__((ext_vector_type(4))) float f32x4;

#define BB 16
#define MM 2048
#define NN 2048

static __device__ __forceinline__ unsigned int cvtpk(float lo, float hi) {
  unsigned int r;
  asm("v_cvt_pk_bf16_f32 %0, %1, %2" : "=v"(r) : "v"(lo), "v"(hi));
  return r;
}
static __device__ __forceinline__ float rdlane(float v, int l) {
  return __uint_as_float(__builtin_amdgcn_readlane(__float_as_uint(v), l));
}

// in: [B, nrows, 64] f32 -> out: [B, 64, nrows] bf16  (used once, for v)
__global__ void transpose_cvt(const float* __restrict__ in,
                              unsigned short* __restrict__ out, int nrows) {
  __shared__ float t[64][65];
  int b = blockIdx.y;
  int n0 = blockIdx.x * 64;
  int tid = threadIdx.x;
  int lane = tid & 63;
  int q = tid >> 6;
  const float* inb = in + ((size_t)b * nrows + n0) * 64;
#pragma unroll
  for (int i = 0; i < 16; ++i) {
    int n = q * 16 + i;
    t[n][lane] = inb[n * 64 + lane];
  }
  __syncthreads();
  unsigned short* outb = out + (size_t)b * 64 * nrows + n0;
  int pr = tid & 31, rq = tid >> 5;
#pragma unroll
  for (int i = 0; i < 8; ++i) {
    int r = rq + 8 * i;
    int n = 2 * pr;
    *(unsigned int*)(outb + (size_t)r * nrows + n) = cvtpk(t[n][r], t[n + 1][r]);
  }
}

// a[b][m][r] = sum_n x[b][m][n]*v[b][n][r] + fused gram (bmat = vT*vT^T).
// NEW vs r17: (1) B-panel staged into LDS per chunk (8KB DMA, dbuf) ->
// B-reads become ds_read_b128 instead of per-kh L2/L3 chain-waits, and
// B traffic drops 4x. (2) XCD-aware flat remap: batch b -> XCD b&7, so each
// XCD L2 holds only 2 B-panels (512KB << 4MB) -> B DMA hits L2.
// grid (M/64, B) launched 2D, remapped internally. block 256.
__global__ void __launch_bounds__(256, 2)
gemm_xv_g(const float* __restrict__ x,
          const unsigned short* __restrict__ vT,
          float* __restrict__ a, float* __restrict__ bmat) {
  __shared__ char smem[49152];  // A: 2x16KB @0, B: 2x8KB @32768
  int flat = blockIdx.x + gridDim.x * blockIdx.y;
  int b = ((flat >> 8) << 3) | (flat & 7);   // batch -> XCD b&7 (bijective)
  int m0 = ((flat >> 3) & 31) * 64;
  int tid = threadIdx.x;
  int w = tid >> 6, l = tid & 63;
  int lr = l & 15, g = l >> 4;
  const unsigned short* vb = vT + (size_t)b * 64 * NN;
  const char* xg0 = (const char*)x + ((size_t)b * MM + m0) * (size_t)(NN * 4);
  f32x4 acc[4] = {};
  f32x4 gacc[4] = {};
  int rowb = (w * 16 + lr) * 256;
  int key = lr & 7;

#define XVSTAGE(DB, CH)                                                         \
  {                                                                             \
    char* lbs = (char*)smem + (DB)*16384;                                       \
    _Pragma("unroll")                                                           \
    for (int i = 0; i < 4; ++i) {                                               \
      int s = w * 4 + i;                                                        \
      int lg = ((l & 15) ^ ((s & 1) * 4 + (l >> 4))) * 16;                      \
      const char* gp = xg0 + (size_t)(s * 4 + (l >> 4)) * (NN * 4) +            \
                       (CH)*256 + lg;                                           \
      __builtin_amdgcn_global_load_lds(                                         \
          (const __attribute__((address_space(1))) unsigned int*)gp,            \
          (__attribute__((address_space(3))) unsigned int*)(lbs + s * 1024),    \
          16, 0, 0);                                                            \
    }                                                                           \
    char* bbs = (char*)smem + 32768 + (DB)*8192;                                \
    _Pragma("unroll")                                                           \
    for (int i = 0; i < 2; ++i) {                                               \
      int bi = w * 2 + i;                                                       \
      int row = bi * 8 + (l >> 3);                                              \
      int q8 = l & 7;                                                           \
      const char* gp = (const char*)vb + (size_t)row * (NN * 2) + (CH)*128 +    \
                       ((q8 ^ (row & 7)) * 16);                                 \
      __builtin_amdgcn_global_load_lds(                                         \
          (const __attribute__((address_space(1))) unsigned int*)gp,            \
          (__attribute__((address_space(3))) unsigned int*)(bbs + bi * 1024),   \
          16, 0, 0);                                                            \
    }                                                                           \
  }

  XVSTAGE(0, 0);
  __syncthreads();
  for (int c = 0; c < 32; ++c) {
    int db = c & 1;
    if (c + 1 < 32) XVSTAGE(db ^ 1, c + 1);
    const char* lb = (const char*)smem + db * 16384 + rowb;
    const char* Bb = (const char*)smem + 32768 + db * 8192;
#pragma unroll
    for (int kh = 0; kh < 2; ++kh) {
      f32x4 lo = *(const f32x4*)(lb + ((kh * 8 + 2 * g + 0) ^ key) * 16);
      f32x4 hi = *(const f32x4*)(lb + ((kh * 8 + 2 * g + 1) ^ key) * 16);
      union { short8 s; unsigned int u[4]; } af;
      af.u[0] = cvtpk(lo[0], lo[1]);
      af.u[1] = cvtpk(lo[2], lo[3]);
      af.u[2] = cvtpk(hi[0], hi[1]);
      af.u[3] = cvtpk(hi[2], hi[3]);
      short8 bfbuf[4];
#pragma unroll
      for (int i = 0; i < 4; ++i) {
        int row = ((w + i) & 3) * 16 + lr;
        bfbuf[i] = *(const short8*)(Bb + row * 128 +
                                    (((kh * 4 + g) ^ (row & 7)) * 16));
      }
#pragma unroll
      for (int i = 0; i < 4; ++i)
        acc[i] = __builtin_amdgcn_mfma_f32_16x16x32_bf16(af.s, bfbuf[i], acc[i], 0, 0, 0);
#pragma unroll
      for (int i = 0; i < 4; ++i)
        gacc[i] = __builtin_amdgcn_mfma_f32_16x16x32_bf16(bfbuf[0], bfbuf[i], gacc[i], 0, 0, 0);
    }
    __syncthreads();
  }
#undef XVSTAGE

  float* ab = a + ((size_t)b * MM + m0 + w * 16) * 64;
#pragma unroll
  for (int i = 0; i < 4; ++i) {
    int ctv = (w + i) & 3;
#pragma unroll
    for (int j = 0; j < 4; ++j)
      ab[(size_t)(4 * g + j) * 64 + ctv * 16 + lr] = acc[i][j];
  }
  float* bbw = bmat + b * 4096;
#pragma unroll
  for (int i = 0; i < 4; ++i) {
    int ctv = (w + i) & 3;
#pragma unroll
    for (int j = 0; j < 4; ++j)
      bbw[(w * 16 + 4 * g + j) * 64 + ctv * 16 + lr] = gacc[i][j];
  }
}

// a[b][n][r] = sum_m x[b][m][n]*u[b][m][r] + fused gram (bmat = uT*uT^T).
// Same B-LDS staging + XCD remap (with batch reversal kept for L3 reuse).
// grid (N/64, B), block 256.
__global__ void __launch_bounds__(256, 2)
gemm_xtu_g(const float* __restrict__ x,
           const unsigned short* __restrict__ uT,
           float* __restrict__ a, float* __restrict__ bmat) {
  __shared__ char smem[49152];
  int flat = blockIdx.x + gridDim.x * blockIdx.y;
  int b = (BB - 1) - (((flat >> 8) << 3) | (flat & 7));
  int n0 = ((flat >> 3) & 31) * 64;
  int tid = threadIdx.x;
  int w = tid >> 6, l = tid & 63;
  int lr = l & 15, g = l >> 4;
  const unsigned short* ub = uT + (size_t)b * 64 * MM;
  const char* xg0 = (const char*)x + ((size_t)b * MM * NN + n0) * 4;
  f32x4 acc[4] = {};
  f32x4 gacc[4] = {};
  int slotX = ((w * 4 + (lr >> 2)) ^ ((g & 1) << 2)) * 16 + (lr & 3) * 4;

#define XTSTAGE(DB, CH)                                                         \
  {                                                                             \
    char* lbs = (char*)smem + (DB)*16384;                                       \
    _Pragma("unroll")                                                           \
    for (int i = 0; i < 4; ++i) {                                               \
      int s = w * 4 + i;                                                        \
      int lg = ((l & 15) ^ (((s >> 1) & 1) << 2)) * 16;                         \
      const char* gp = xg0 + (size_t)((CH)*64 + s * 4 + (l >> 4)) * (NN * 4) +  \
                       lg;                                                      \
      __builtin_amdgcn_global_load_lds(                                         \
          (const __attribute__((address_space(1))) unsigned int*)gp,            \
          (__attribute__((address_space(3))) unsigned int*)(lbs + s * 1024),    \
          16, 0, 0);                                                            \
    }                                                                           \
    char* bbs = (char*)smem + 32768 + (DB)*8192;                                \
    _Pragma("unroll")                                                           \
    for (int i = 0; i < 2; ++i) {                                               \
      int bi = w * 2 + i;                                                       \
      int row = bi * 8 + (l >> 3);                                              \
      int q8 = l & 7;                                                           \
      const char* gp = (const char*)ub + (size_t)row * (MM * 2) + (CH)*128 +    \
                       ((q8 ^ (row & 7)) * 16);                                 \
      __builtin_amdgcn_global_load_lds(                                         \
          (const __attribute__((address_space(1))) unsigned int*)gp,            \
          (__attribute__((address_space(3))) unsigned int*)(bbs + bi * 1024),   \
          16, 0, 0);                                                            \
    }                                                                           \
  }

  XTSTAGE(0, 0);
  __syncthreads();
  for (int c = 0; c < 32; ++c) {
    int db = c & 1;
    if (c + 1 < 32) XTSTAGE(db ^ 1, c + 1);
    const char* lb = (const char*)smem + db * 16384 + slotX;
    const char* Bb = (const char*)smem + 32768 + db * 8192;
#pragma unroll
    for (int kh = 0; kh < 2; ++kh) {
      const char* lk = lb + (kh * 32 + 8 * g) * 256;
      float vv[8];
#pragma unroll
      for (int j = 0; j < 8; ++j)
        vv[j] = *(const float*)(lk + j * 256);
      union { short8 s; unsigned int u[4]; } af;
      af.u[0] = cvtpk(vv[0], vv[1]);
      af.u[1] = cvtpk(vv[2], vv[3]);
      af.u[2] = cvtpk(vv[4], vv[5]);
      af.u[3] = cvtpk(vv[6], vv[7]);
      short8 bfbuf[4];
#pragma unroll
      for (int i = 0; i < 4; ++i) {
        int row = ((w + i) & 3) * 16 + lr;
        bfbuf[i] = *(const short8*)(Bb + row * 128 +
                                    (((kh * 4 + g) ^ (row & 7)) * 16));
      }
#pragma unroll
      for (int i = 0; i < 4; ++i)
        acc[i] = __builtin_amdgcn_mfma_f32_16x16x32_bf16(af.s, bfbuf[i], acc[i], 0, 0, 0);
#pragma unroll
      for (int i = 0; i < 4; ++i)
        gacc[i] = __builtin_amdgcn_mfma_f32_16x16x32_bf16(bfbuf[0], bfbuf[i], gacc[i], 0, 0, 0);
    }
    __syncthreads();
  }
#undef XTSTAGE

  float* ab = a + ((size_t)b * NN + n0 + w * 16) * 64;
#pragma unroll
  for (int i = 0; i < 4; ++i) {
    int ctv = (w + i) & 3;
#pragma unroll
    for (int j = 0; j < 4; ++j)
      ab[(size_t)(4 * g + j) * 64 + ctv * 16 + lr] = acc[i][j];
  }
  float* bbw = bmat + b * 4096;
#pragma unroll
  for (int i = 0; i < 4; ++i) {
    int ctv = (w + i) & 3;
#pragma unroll
    for (int j = 0; j < 4; ++j)
      bbw[(w * 16 + 4 * g + j) * 64 + ctv * 16 + lr] = gacc[i][j];
  }
}

// Coordinate descent, one THREAD per row, PLUS fused bf16-transpose output.
// grid (nrows/64, B), block 64 (1 wave).
__global__ void __launch_bounds__(64, 1)
cd_t(const float* __restrict__ u_in,
     const float* __restrict__ a_ws,
     const float* __restrict__ bmat,
     float* __restrict__ u_out,
     unsigned short* __restrict__ tT,
     float l1, float l2e, int nrows, int doT) {
  __shared__ float ls[64][65];
  int b = blockIdx.y;
  int m0 = blockIdx.x * 64;
  int t = threadIdx.x;
  size_t base = ((size_t)b * nrows + m0 + t) * 64;
  const float* bb = bmat + b * 4096;
  float uu[64], aa[64];
#pragma unroll
  for (int i = 0; i < 16; ++i) {
    *(f32x4*)(uu + 4 * i) = *(const f32x4*)(u_in + base + 4 * i);
    *(f32x4*)(aa + 4 * i) = *(const f32x4*)(a_ws + base + 4 * i);
  }
  float invl = 1.0f / (bb[t * 65] + l2e);
#pragma unroll
  for (int r = 0; r < 64; ++r) {
    float s0 = 0.f, s1 = 0.f, s2 = 0.f, s3 = 0.f;
#pragma unroll
    for (int j = 0; j < 64; j += 4) {
      s0 = fmaf(uu[j + 0], bb[r * 64 + j + 0], s0);
      s1 = fmaf(uu[j + 1], bb[r * 64 + j + 1], s1);
      s2 = fmaf(uu[j + 2], bb[r * 64 + j + 2], s2);
      s3 = fmaf(uu[j + 3], bb[r * 64 + j + 3], s3);
    }
    float s = (s0 + s1) + (s2 + s3);
    float brr = bb[r * 65];                      // uniform -> SGPR
    float num = fmaf(uu[r], brr, aa[r] - s);     // a_r - (s - u_r*b_rr)
    float cl = fminf(fmaxf(num, -l1), l1);       // v_med3
    uu[r] = (num - cl) * rdlane(invl, r);        // soft-thr / (b_rr+l2e)
  }
#pragma unroll
  for (int i = 0; i < 16; ++i)
    *(f32x4*)(u_out + base + 4 * i) = *(const f32x4*)(uu + 4 * i);

  if (doT) {
#pragma unroll
    for (int j = 0; j < 64; ++j) ls[t][j] = uu[j];
    __syncthreads();
    unsigned short* outb = tT + (size_t)b * 64 * nrows + m0;
    int q = t & 31, h = t >> 5;
#pragma unroll
    for (int cc = 0; cc < 32; ++cc) {
      int c0 = cc * 2 + h;
      *(unsigned int*)(outb + (size_t)c0 * nrows + 2 * q) =
          cvtpk(ls[2 * q][c0], ls[2 * q + 1][c0]);
    }
  }
}

extern "C" void kernel_launch(void* const* d_in, const int* in_sizes, int n_in,
                              void* d_out, int out_size, void* d_ws, size_t ws_size,
                              hipStream_t stream) {
  (void)in_sizes; (void)n_in; (void)out_size; (void)ws_size;
  const float* x = (const float*)d_in[0];
  const float* u = (const float*)d_in[1];
  const float* v = (const float*)d_in[2];
  float* u_out = (float*)d_out;
  float* v_out = u_out + (size_t)BB * MM * 64;

  float* a_ws = (float*)d_ws;                                        // 8.39 MB
  float* b_ws = (float*)((char*)d_ws + (size_t)BB * MM * 64 * 4);    // 256 KB
  unsigned short* tT = (unsigned short*)((char*)b_ws + (size_t)BB * 4096 * 4);

  float l1u = (float)(0.01 * 0.1 * (double)NN);
  float l2u = (float)(0.01 * 0.9 * (double)NN + 1e-16);
  float l1v = (float)(0.01 * 0.1 * (double)MM);
  float l2v = (float)(0.01 * 0.9 * (double)MM + 1e-16);

  // ---- factor 0: update u (gram fused into xv; uT emitted by cd) ----
  transpose_cvt<<<dim3(NN / 64, BB), 256, 0, stream>>>(v, tT, NN);
  gemm_xv_g<<<dim3(MM / 64, BB), 256, 0, stream>>>(x, tT, a_ws, b_ws);
  cd_t<<<dim3(MM / 64, BB), 64, 0, stream>>>(u, a_ws, b_ws, u_out, tT, l1u, l2u, MM, 1);

  // ---- factor 1: update v (uses new u via tT; gram fused into xtu) ----
  gemm_xtu_g<<<dim3(NN / 64, BB), 256, 0, stream>>>(x, tT, a_ws, b_ws);
  cd_t<<<dim3(NN / 64, BB), 64, 0, stream>>>(v, a_ws, b_ws, v_out, tT, l1v, l2v, NN, 0);
}

// Round 19
// 187.076 us; speedup vs baseline: 1.5469x; 1.0010x over previous
//
#include <hip/hip_runtime.h>

typedef __attribute__((ext_vector_type(8))) short short8;
typedef __attribute__((ext_vector_type(4))) float f32x4;

#define BB 16
#define MM 2048
#define NN 2048

static __device__ __forceinline__ unsigned int cvtpk(float lo, float hi) {
  unsigned int r;
  asm("v_cvt_pk_bf16_f32 %0, %1, %2" : "=v"(r) : "v"(lo), "v"(hi));
  return r;
}
static __device__ __forceinline__ float rdlane(float v, int l) {
  return __uint_as_float(__builtin_amdgcn_readlane(__float_as_uint(v), l));
}

#define WAITV(N)                                            \
  do {                                                      \
    asm volatile("s_waitcnt vmcnt(" #N ")" ::: "memory");   \
    __builtin_amdgcn_sched_barrier(0);                      \
  } while (0)
#define BAR() __builtin_amdgcn_s_barrier()

// in: [B, nrows, 64] f32 -> out: [B, 64, nrows] bf16  (used once, for v)
__global__ void transpose_cvt(const float* __restrict__ in,
                              unsigned short* __restrict__ out, int nrows) {
  __shared__ float t[64][65];
  int b = blockIdx.y;
  int n0 = blockIdx.x * 64;
  int tid = threadIdx.x;
  int lane = tid & 63;
  int q = tid >> 6;
  const float* inb = in + ((size_t)b * nrows + n0) * 64;
#pragma unroll
  for (int i = 0; i < 16; ++i) {
    int n = q * 16 + i;
    t[n][lane] = inb[n * 64 + lane];
  }
  __syncthreads();
  unsigned short* outb = out + (size_t)b * 64 * nrows + n0;
  int pr = tid & 31, rq = tid >> 5;
#pragma unroll
  for (int i = 0; i < 8; ++i) {
    int r = rq + 8 * i;
    int n = 2 * pr;
    *(unsigned int*)(outb + (size_t)r * nrows + n) = cvtpk(t[n][r], t[n + 1][r]);
  }
}

// a[b][m][r] = sum_n x[b][m][n]*v[b][n][r] + fused gram (bmat = vT*vT^T).
// vs r18: 3-deep stage buffers + counted s_waitcnt vmcnt(6) + raw s_barrier
// (never drains the DMA FIFO to 0 in the main loop — T3/T4, now valid since
// ALL traffic is global_load_lds). A: 3x16KB, B: 3x8KB = 72KB, 2 blocks/CU.
// XCD remap: batch -> XCD b&7. grid (M/64, B), block 256.
__global__ void __launch_bounds__(256, 2)
gemm_xv_g(const float* __restrict__ x,
          const unsigned short* __restrict__ vT,
          float* __restrict__ a, float* __restrict__ bmat) {
  __shared__ char smem[73728];  // A bufs @0,16K,32K; B bufs @48K,56K,64K
  int flat = blockIdx.x + gridDim.x * blockIdx.y;
  int b = ((flat >> 8) << 3) | (flat & 7);   // batch -> XCD b&7 (bijective)
  int m0 = ((flat >> 3) & 31) * 64;
  int tid = threadIdx.x;
  int w = tid >> 6, l = tid & 63;
  int lr = l & 15, g = l >> 4;
  const unsigned short* vb = vT + (size_t)b * 64 * NN;
  const char* xg0 = (const char*)x + ((size_t)b * MM + m0) * (size_t)(NN * 4);
  f32x4 acc[4] = {};
  f32x4 gacc[4] = {};
  int rowb = (w * 16 + lr) * 256;
  int key = lr & 7;

#define XVSTAGE(DB, CH)                                                         \
  {                                                                             \
    char* lbs = (char*)smem + (DB)*16384;                                       \
    _Pragma("unroll")                                                           \
    for (int i = 0; i < 4; ++i) {                                               \
      int s = w * 4 + i;                                                        \
      int lg = ((l & 15) ^ ((s & 1) * 4 + (l >> 4))) * 16;                      \
      const char* gp = xg0 + (size_t)(s * 4 + (l >> 4)) * (NN * 4) +            \
                       (CH)*256 + lg;                                           \
      __builtin_amdgcn_global_load_lds(                                         \
          (const __attribute__((address_space(1))) unsigned int*)gp,            \
          (__attribute__((address_space(3))) unsigned int*)(lbs + s * 1024),    \
          16, 0, 0);                                                            \
    }                                                                           \
    char* bbs = (char*)smem + 49152 + (DB)*8192;                                \
    _Pragma("unroll")                                                           \
    for (int i = 0; i < 2; ++i) {                                               \
      int bi = w * 2 + i;                                                       \
      int row = bi * 8 + (l >> 3);                                              \
      int q8 = l & 7;                                                           \
      const char* gp = (const char*)vb + (size_t)row * (NN * 2) + (CH)*128 +    \
                       ((q8 ^ (row & 7)) * 16);                                 \
      __builtin_amdgcn_global_load_lds(                                         \
          (const __attribute__((address_space(1))) unsigned int*)gp,            \
          (__attribute__((address_space(3))) unsigned int*)(bbs + bi * 1024),   \
          16, 0, 0);                                                            \
    }                                                                           \
  }

#define XVCOMP(DB, CH)                                                          \
  {                                                                             \
    const char* lb = (const char*)smem + (DB)*16384 + rowb;                     \
    const char* Bb = (const char*)smem + 49152 + (DB)*8192;                     \
    _Pragma("unroll")                                                           \
    for (int kh = 0; kh < 2; ++kh) {                                            \
      f32x4 lo = *(const f32x4*)(lb + ((kh * 8 + 2 * g + 0) ^ key) * 16);       \
      f32x4 hi = *(const f32x4*)(lb + ((kh * 8 + 2 * g + 1) ^ key) * 16);       \
      union { short8 s; unsigned int u[4]; } af;                                \
      af.u[0] = cvtpk(lo[0], lo[1]);                                            \
      af.u[1] = cvtpk(lo[2], lo[3]);                                            \
      af.u[2] = cvtpk(hi[0], hi[1]);                                            \
      af.u[3] = cvtpk(hi[2], hi[3]);                                            \
      short8 bfbuf[4];                                                          \
      _Pragma("unroll")                                                         \
      for (int i = 0; i < 4; ++i) {                                             \
        int row = ((w + i) & 3) * 16 + lr;                                      \
        bfbuf[i] = *(const short8*)(Bb + row * 128 +                            \
                                    (((kh * 4 + g) ^ (row & 7)) * 16));         \
      }                                                                         \
      _Pragma("unroll")                                                         \
      for (int i = 0; i < 4; ++i)                                               \
        acc[i] = __builtin_amdgcn_mfma_f32_16x16x32_bf16(af.s, bfbuf[i],        \
                                                         acc[i], 0, 0, 0);      \
      _Pragma("unroll")                                                         \
      for (int i = 0; i < 4; ++i)                                               \
        gacc[i] = __builtin_amdgcn_mfma_f32_16x16x32_bf16(bfbuf[0], bfbuf[i],   \
                                                          gacc[i], 0, 0, 0);    \
    }                                                                           \
  }

  XVSTAGE(0, 0);
  XVSTAGE(1, 1);
  {
    int cur = 0, stg = 2;
    for (int c = 0; c < 30; ++c) {
      WAITV(6); BAR();
      XVSTAGE(stg, c + 2);
      XVCOMP(cur, c);
      cur = (cur == 2) ? 0 : cur + 1;
      stg = (stg == 2) ? 0 : stg + 1;
    }
    WAITV(6); BAR(); XVCOMP(cur, 30);
    cur = (cur == 2) ? 0 : cur + 1;
    WAITV(0); BAR(); XVCOMP(cur, 31);
  }
#undef XVSTAGE
#undef XVCOMP

  float* ab = a + ((size_t)b * MM + m0 + w * 16) * 64;
#pragma unroll
  for (int i = 0; i < 4; ++i) {
    int ctv = (w + i) & 3;
#pragma unroll
    for (int j = 0; j < 4; ++j)
      ab[(size_t)(4 * g + j) * 64 + ctv * 16 + lr] = acc[i][j];
  }
  float* bbw = bmat + b * 4096;
#pragma unroll
  for (int i = 0; i < 4; ++i) {
    int ctv = (w + i) & 3;
#pragma unroll
    for (int j = 0; j < 4; ++j)
      bbw[(w * 16 + 4 * g + j) * 64 + ctv * 16 + lr] = gacc[i][j];
  }
}

// a[b][n][r] = sum_m x[b][m][n]*u[b][m][r] + fused gram (bmat = uT*uT^T).
// Same 3-deep counted-vmcnt pipeline. Batch reversal kept for L3 reuse.
// grid (N/64, B), block 256.
__global__ void __launch_bounds__(256, 2)
gemm_xtu_g(const float* __restrict__ x,
           const unsigned short* __restrict__ uT,
           float* __restrict__ a, float* __restrict__ bmat) {
  __shared__ char smem[73728];
  int flat = blockIdx.x + gridDim.x * blockIdx.y;
  int b = (BB - 1) - (((flat >> 8) << 3) | (flat & 7));
  int n0 = ((flat >> 3) & 31) * 64;
  int tid = threadIdx.x;
  int w = tid >> 6, l = tid & 63;
  int lr = l & 15, g = l >> 4;
  const unsigned short* ub = uT + (size_t)b * 64 * MM;
  const char* xg0 = (const char*)x + ((size_t)b * MM * NN + n0) * 4;
  f32x4 acc[4] = {};
  f32x4 gacc[4] = {};
  int slotX = ((w * 4 + (lr >> 2)) ^ ((g & 1) << 2)) * 16 + (lr & 3) * 4;

#define XTSTAGE(DB, CH)                                                         \
  {                                                                             \
    char* lbs = (char*)smem + (DB)*16384;                                       \
    _Pragma("unroll")                                                           \
    for (int i = 0; i < 4; ++i) {                                               \
      int s = w * 4 + i;                                                        \
      int lg = ((l & 15) ^ (((s >> 1) & 1) << 2)) * 16;                         \
      const char* gp = xg0 + (size_t)((CH)*64 + s * 4 + (l >> 4)) * (NN * 4) +  \
                       lg;                                                      \
      __builtin_amdgcn_global_load_lds(                                         \
          (const __attribute__((address_space(1))) unsigned int*)gp,            \
          (__attribute__((address_space(3))) unsigned int*)(lbs + s * 1024),    \
          16, 0, 0);                                                            \
    }                                                                           \
    char* bbs = (char*)smem + 49152 + (DB)*8192;                                \
    _Pragma("unroll")                                                           \
    for (int i = 0; i < 2; ++i) {                                               \
      int bi = w * 2 + i;                                                       \
      int row = bi * 8 + (l >> 3);                                              \
      int q8 = l & 7;                                                           \
      const char* gp = (const char*)ub + (size_t)row * (MM * 2) + (CH)*128 +    \
                       ((q8 ^ (row & 7)) * 16);                                 \
      __builtin_amdgcn_global_load_lds(                                         \
          (const __attribute__((address_space(1))) unsigned int*)gp,            \
          (__attribute__((address_space(3))) unsigned int*)(bbs + bi * 1024),   \
          16, 0, 0);                                                            \
    }                                                                           \
  }

#define XTCOMP(DB, CH)                                                          \
  {                                                                             \
    const char* lb = (const char*)smem + (DB)*16384 + slotX;                    \
    const char* Bb = (const char*)smem + 49152 + (DB)*8192;                     \
    _Pragma("unroll")                                                           \
    for (int kh = 0; kh < 2; ++kh) {                                            \
      const char* lk = lb + (kh * 32 + 8 * g) * 256;                            \
      float vv[8];                                                              \
      _Pragma("unroll")                                                         \
      for (int j = 0; j < 8; ++j)                                               \
        vv[j] = *(const float*)(lk + j * 256);                                  \
      union { short8 s; unsigned int u[4]; } af;                                \
      af.u[0] = cvtpk(vv[0], vv[1]);                                            \
      af.u[1] = cvtpk(vv[2], vv[3]);                                            \
      af.u[2] = cvtpk(vv[4], vv[5]);                                            \
      af.u[3] = cvtpk(vv[6], vv[7]);                                            \
      short8 bfbuf[4];                                                          \
      _Pragma("unroll")                                                         \
      for (int i = 0; i < 4; ++i) {                                             \
        int row = ((w + i) & 3) * 16 + lr;                                      \
        bfbuf[i] = *(const short8*)(Bb + row * 128 +                            \
                                    (((kh * 4 + g) ^ (row & 7)) * 16));         \
      }                                                                         \
      _Pragma("unroll")                                                         \
      for (int i = 0; i < 4; ++i)                                               \
        acc[i] = __builtin_amdgcn_mfma_f32_16x16x32_bf16(af.s, bfbuf[i],        \
                                                         acc[i], 0, 0, 0);      \
      _Pragma("unroll")                                                         \
      for (int i = 0; i < 4; ++i)                                               \
        gacc[i] = __builtin_amdgcn_mfma_f32_16x16x32_bf16(bfbuf[0], bfbuf[i],   \
                                                          gacc[i], 0, 0, 0);    \
    }                                                                           \
  }

  XTSTAGE(0, 0);
  XTSTAGE(1, 1);
  {
    int cur = 0, stg = 2;
    for (int c = 0; c < 30; ++c) {
      WAITV(6); BAR();
      XTSTAGE(stg, c + 2);
      XTCOMP(cur, c);
      cur = (cur == 2) ? 0 : cur + 1;
      stg = (stg == 2) ? 0 : stg + 1;
    }
    WAITV(6); BAR(); XTCOMP(cur, 30);
    cur = (cur == 2) ? 0 : cur + 1;
    WAITV(0); BAR(); XTCOMP(cur, 31);
  }
#undef XTSTAGE
#undef XTCOMP

  float* ab = a + ((size_t)b * NN + n0 + w * 16) * 64;
#pragma unroll
  for (int i = 0; i < 4; ++i) {
    int ctv = (w + i) & 3;
#pragma unroll
    for (int j = 0; j < 4; ++j)
      ab[(size_t)(4 * g + j) * 64 + ctv * 16 + lr] = acc[i][j];
  }
  float* bbw = bmat + b * 4096;
#pragma unroll
  for (int i = 0; i < 4; ++i) {
    int ctv = (w + i) & 3;
#pragma unroll
    for (int j = 0; j < 4; ++j)
      bbw[(w * 16 + 4 * g + j) * 64 + ctv * 16 + lr] = gacc[i][j];
  }
}

// Coordinate descent, one THREAD per row, PLUS fused bf16-transpose output.
// grid (nrows/64, B), block 64 (1 wave).
__global__ void __launch_bounds__(64, 1)
cd_t(const float* __restrict__ u_in,
     const float* __restrict__ a_ws,
     const float* __restrict__ bmat,
     float* __restrict__ u_out,
     unsigned short* __restrict__ tT,
     float l1, float l2e, int nrows, int doT) {
  __shared__ float ls[64][65];
  int b = blockIdx.y;
  int m0 = blockIdx.x * 64;
  int t = threadIdx.x;
  size_t base = ((size_t)b * nrows + m0 + t) * 64;
  const float* bb = bmat + b * 4096;
  float uu[64], aa[64];
#pragma unroll
  for (int i = 0; i < 16; ++i) {
    *(f32x4*)(uu + 4 * i) = *(const f32x4*)(u_in + base + 4 * i);
    *(f32x4*)(aa + 4 * i) = *(const f32x4*)(a_ws + base + 4 * i);
  }
  float invl = 1.0f / (bb[t * 65] + l2e);
#pragma unroll
  for (int r = 0; r < 64; ++r) {
    float s0 = 0.f, s1 = 0.f, s2 = 0.f, s3 = 0.f;
#pragma unroll
    for (int j = 0; j < 64; j += 4) {
      s0 = fmaf(uu[j + 0], bb[r * 64 + j + 0], s0);
      s1 = fmaf(uu[j + 1], bb[r * 64 + j + 1], s1);
      s2 = fmaf(uu[j + 2], bb[r * 64 + j + 2], s2);
      s3 = fmaf(uu[j + 3], bb[r * 64 + j + 3], s3);
    }
    float s = (s0 + s1) + (s2 + s3);
    float brr = bb[r * 65];                      // uniform -> SGPR
    float num = fmaf(uu[r], brr, aa[r] - s);     // a_r - (s - u_r*b_rr)
    float cl = fminf(fmaxf(num, -l1), l1);       // v_med3
    uu[r] = (num - cl) * rdlane(invl, r);        // soft-thr / (b_rr+l2e)
  }
#pragma unroll
  for (int i = 0; i < 16; ++i)
    *(f32x4*)(u_out + base + 4 * i) = *(const f32x4*)(uu + 4 * i);

  if (doT) {
#pragma unroll
    for (int j = 0; j < 64; ++j) ls[t][j] = uu[j];
    __syncthreads();
    unsigned short* outb = tT + (size_t)b * 64 * nrows + m0;
    int q = t & 31, h = t >> 5;
#pragma unroll
    for (int cc = 0; cc < 32; ++cc) {
      int c0 = cc * 2 + h;
      *(unsigned int*)(outb + (size_t)c0 * nrows + 2 * q) =
          cvtpk(ls[2 * q][c0], ls[2 * q + 1][c0]);
    }
  }
}

extern "C" void kernel_launch(void* const* d_in, const int* in_sizes, int n_in,
                              void* d_out, int out_size, void* d_ws, size_t ws_size,
                              hipStream_t stream) {
  (void)in_sizes; (void)n_in; (void)out_size; (void)ws_size;
  const float* x = (const float*)d_in[0];
  const float* u = (const float*)d_in[1];
  const float* v = (const float*)d_in[2];
  float* u_out = (float*)d_out;
  float* v_out = u_out + (size_t)BB * MM * 64;

  float* a_ws = (float*)d_ws;                                        // 8.39 MB
  float* b_ws = (float*)((char*)d_ws + (size_t)BB * MM * 64 * 4);    // 256 KB
  unsigned short* tT = (unsigned short*)((char*)b_ws + (size_t)BB * 4096 * 4);

  float l1u = (float)(0.01 * 0.1 * (double)NN);
  float l2u = (float)(0.01 * 0.9 * (double)NN + 1e-16);
  float l1v = (float)(0.01 * 0.1 * (double)MM);
  float l2v = (float)(0.01 * 0.9 * (double)MM + 1e-16);

  // ---- factor 0: update u (gram fused into xv; uT emitted by cd) ----
  transpose_cvt<<<dim3(NN / 64, BB), 256, 0, stream>>>(v, tT, NN);
  gemm_xv_g<<<dim3(MM / 64, BB), 256, 0, stream>>>(x, tT, a_ws, b_ws);
  cd_t<<<dim3(MM / 64, BB), 64, 0, stream>>>(u, a_ws, b_ws, u_out, tT, l1u, l2u, MM, 1);

  // ---- factor 1: update v (uses new u via tT; gram fused into xtu) ----
  gemm_xtu_g<<<dim3(NN / 64, BB), 256, 0, stream>>>(x, tT, a_ws, b_ws);
  cd_t<<<dim3(NN / 64, BB), 64, 0, stream>>>(v, a_ws, b_ws, v_out, tT, l1v, l2v, NN, 0);
}